// Round 1
// baseline (4769.344 us; speedup 1.0000x reference)
//
#include <hip/hip_runtime.h>
#include <stdint.h>

static constexpr int MAXBLK = 2048;   // workspace sizing + scan unroll bound
static constexpr int NTHR = 256;
static constexpr uint32_t INF32 = 0x7fffffffu;
static constexpr uint32_t DEADB = 0x40000000u;  // death tag base: DEADB + round
static constexpr uint32_t MAGIC = 0x13579BDFu;

// Lightweight grid barrier: monotone arrive counter bc[0], release word bc[1].
// Agent-scope atomics + __threadfence for cross-XCD visibility (mirrors the
// memory semantics of cg::grid_group::sync, minus its overhead).
__device__ inline void gbar(uint32_t* bc, uint32_t& bk) {
  __syncthreads();
  if (threadIdx.x == 0) {
    __threadfence();   // release: drain + write back this XCD's L2
    bk++;
    uint32_t old = __hip_atomic_fetch_add(&bc[0], 1u, __ATOMIC_RELAXED,
                                          __HIP_MEMORY_SCOPE_AGENT);
    if (old == bk * gridDim.x - 1u) {
      __hip_atomic_store(&bc[1], bk, __ATOMIC_RELAXED, __HIP_MEMORY_SCOPE_AGENT);
    } else {
      uint32_t r;
      do {
        __builtin_amdgcn_s_sleep(1);
        r = __hip_atomic_load(&bc[1], __ATOMIC_RELAXED, __HIP_MEMORY_SCOPE_AGENT);
      } while ((int32_t)(r - bk) < 0);
    }
    __threadfence();   // acquire: invalidate stale L1/L2 lines
  }
  __syncthreads();
}

// Hierarchical exclusive scan; out[i]=exclusive prefix, returns grand total.
// Grid size is runtime (gridDim.x, a multiple of NTHR, <= MAXBLK).
template <typename F>
__device__ uint32_t grid_exscan(uint32_t L, F getv, uint32_t* __restrict__ out,
                                uint32_t* __restrict__ bsum, uint32_t* bc,
                                uint32_t& bk) {
  __shared__ uint32_t sh[NTHR];
  const uint32_t nblk = gridDim.x;
  const uint32_t ntot = nblk * (uint32_t)NTHR;
  const uint32_t t = blockIdx.x * blockDim.x + threadIdx.x;
  const uint32_t chunk = (L + ntot - 1) / ntot;
  const uint32_t lo = t * chunk;
  const uint32_t hi = (lo + chunk < L) ? (lo + chunk) : L;
  uint32_t s = 0;
  for (uint32_t i = lo; i < hi; ++i) s += getv(i);
  sh[threadIdx.x] = s;
  __syncthreads();
  for (int off = 1; off < NTHR; off <<= 1) {
    uint32_t add = (threadIdx.x >= (uint32_t)off) ? sh[threadIdx.x - off] : 0u;
    __syncthreads();
    sh[threadIdx.x] += add;
    __syncthreads();
  }
  uint32_t excl_in_blk = sh[threadIdx.x] - s;
  if (threadIdx.x == NTHR - 1) bsum[blockIdx.x] = sh[NTHR - 1];
  gbar(bc, bk);
  if (blockIdx.x == 0) {
    constexpr int MAXPER = MAXBLK / NTHR;  // 8
    const uint32_t per = nblk / (uint32_t)NTHR;  // exact: grid % NTHR == 0
    uint32_t loc[MAXPER];
    uint32_t ls = 0;
#pragma unroll
    for (uint32_t j = 0; j < (uint32_t)MAXPER; ++j) {  // predicated unroll:
      uint32_t v = (j < per) ? bsum[threadIdx.x * per + j] : 0u;  // loc[] stays
      loc[j] = v;                                                 // in regs
      ls += v;
    }
    __syncthreads();
    sh[threadIdx.x] = ls;
    __syncthreads();
    for (int off = 1; off < NTHR; off <<= 1) {
      uint32_t add = (threadIdx.x >= (uint32_t)off) ? sh[threadIdx.x - off] : 0u;
      __syncthreads();
      sh[threadIdx.x] += add;
      __syncthreads();
    }
    uint32_t run = sh[threadIdx.x] - ls;
#pragma unroll
    for (uint32_t j = 0; j < (uint32_t)MAXPER; ++j) {
      if (j < per) { uint32_t v = loc[j]; bsum[threadIdx.x * per + j] = run; run += v; }
    }
    if (threadIdx.x == NTHR - 1) bsum[nblk] = run;
  }
  gbar(bc, bk);
  uint32_t run = bsum[blockIdx.x] + excl_in_blk;
  for (uint32_t i = lo; i < hi; ++i) { uint32_t g = getv(i); out[i] = run; run += g; }
  gbar(bc, bk);
  return bsum[nblk];
}

// __launch_bounds__(256, 8): 8 waves/SIMD min -> VGPR cap 64 (we use ~16),
// enabling 8 blocks/CU = 32 waves/CU full residency for the cooperative grid.
__global__ void __launch_bounds__(NTHR, 8)
kmis_kernel(const float* __restrict__ x, const int* __restrict__ eidx,
            const float* __restrict__ eattr, const float* __restrict__ score,
            float* __restrict__ out, uint32_t* __restrict__ w,
            int N_, int E_, long long out_size, unsigned long long wcap) {
  const uint32_t N = (uint32_t)N_;
  const uint32_t E = (uint32_t)E_;
  const uint32_t tid = blockIdx.x * blockDim.x + threadIdx.x;
  const uint32_t ntot = gridDim.x * (uint32_t)NTHR;
  const uint32_t lane = threadIdx.x & 63u;
  uint32_t bk = 0;

  // ---- workspace layout (u32 units) ----
  uint32_t* bc     = w;                    // 16 (0 arrive, 1 release, 2 magic)
  uint32_t* cnt    = bc + 16;              // 16
  uint32_t* bsum   = cnt + 16;             // MAXBLK+1
  uint32_t* hist64 = bsum + MAXBLK + 1;    // 65536
  uint32_t* sc     = hist64 + 65536;       // 65536 + N (combined scan output)
  uint32_t* cur64  = sc + 65536 + N;       // 65536 (bucket fill cursors)
  uint32_t* deg    = cur64 + 65536;        // N
  uint32_t* ccur   = deg + N;              // N (CSR fill cursors)
  uint32_t* keys   = ccur + N;             // N
  uint32_t* rank   = keys + N;             // N
  uint32_t* cur    = rank + N;             // N: rank if live, DEADB+round if dead
  uint32_t* mis    = cur + N;              // N
  uint32_t* blist  = mis + N;              // N (buckets; later MIS list id-order)
  uint32_t* frA    = blist + N;            // N
  uint32_t* frB    = frA + N;              // N
  uint32_t* idpos  = frB + N;              // N
  uint32_t* r2ip   = idpos + N;            // N
  uint32_t* clus   = r2ip + N;             // N
  uint32_t* adj    = clus + N;             // E (CSR neighbor array)
  uint32_t* dyn    = adj + E;              // bitmap + wpre

  const int* rowA = eidx;
  const int* colA = eidx + E;

  // ---- handshake: robust barrier-cell init (ws is poisoned 0xAA) ----
  if (blockIdx.x == 0 && threadIdx.x == 0) {
    __hip_atomic_store(&bc[0], 0u, __ATOMIC_RELAXED, __HIP_MEMORY_SCOPE_AGENT);
    __hip_atomic_store(&bc[1], 0u, __ATOMIC_RELAXED, __HIP_MEMORY_SCOPE_AGENT);
    __threadfence();
    __hip_atomic_store(&bc[2], MAGIC, __ATOMIC_RELAXED, __HIP_MEMORY_SCOPE_AGENT);
  }
  if (threadIdx.x == 0) {
    while (__hip_atomic_load(&bc[2], __ATOMIC_RELAXED, __HIP_MEMORY_SCOPE_AGENT) != MAGIC)
      __builtin_amdgcn_s_sleep(1);
    __threadfence();
  }
  __syncthreads();

  // ---- P0: init ----
  for (uint32_t i = tid; i < 65536u; i += ntot) { hist64[i] = 0; cur64[i] = 0; }
  for (uint32_t i = tid; i < N; i += ntot) { deg[i] = 0; ccur[i] = 0; mis[i] = 0; }
  if (tid < 16) cnt[tid] = 0;
  gbar(bc, bk);

  // ---- P1: score keys + bucket histogram; CSR degree count ----
  for (uint32_t i = tid; i < N; i += ntot) {
    uint32_t k = __float_as_uint(score[i]);  // monotone for x>=0
    keys[i] = k;
    atomicAdd(&hist64[k >> 16], 1u);
  }
  for (uint32_t e = tid; e < E; e += ntot) atomicAdd(&deg[(uint32_t)rowA[e]], 1u);
  gbar(bc, bk);

  // ---- P2: combined exclusive scan (bucket starts | row_ptr+N) ----
  grid_exscan(65536u + N,
              [=](uint32_t i) { return (i < 65536u) ? hist64[i] : deg[i - 65536u]; },
              sc, bsum, bc, bk);
  // sc[b] = bucket start; sc[65536+v]-N = CSR row start; row end via v+1 (or E).

  // ---- P3: fill bucket lists + CSR adjacency ----
  for (uint32_t i = tid; i < N; i += ntot) {
    uint32_t b = keys[i] >> 16;
    uint32_t p = sc[b] + atomicAdd(&cur64[b], 1u);
    blist[p] = i;
  }
  for (uint32_t e = tid; e < E; e += ntot) {
    uint32_t r = (uint32_t)rowA[e];
    uint32_t p = (sc[65536u + r] - N) + atomicAdd(&ccur[r], 1u);
    adj[p] = (uint32_t)colA[e];
  }
  gbar(bc, bk);

  // ---- P4: exact stable ranks ----
  for (uint32_t i = tid; i < N; i += ntot) {
    uint32_t ki = keys[i];
    uint32_t b = ki >> 16;
    uint32_t s0 = sc[b], s1 = sc[b + 1];   // sc[65536] == N, safe for b=65535
    uint32_t r = s0;
    for (uint32_t j = s0; j < s1; ++j) {
      uint32_t jj = blist[j];
      uint32_t kj = keys[jj];
      r += (kj < ki || (kj == ki && jj < i)) ? 1u : 0u;
    }
    rank[i] = r;
    cur[i] = r;
  }
  gbar(bc, bk);

  // ---- P5: node-centric MIS, 2 barriers/round, frontier-compacted ----
  uint32_t* frCur = frA;
  uint32_t* frNxt = frB;
  uint32_t flen = N;
  for (uint32_t r = 0; r < 4000u; ++r) {
    uint32_t par = r & 1u;
    if (tid == 0) cnt[1 + par] = 0;
    // A: select local minima among live (reads cur, writes mis only)
    for (uint32_t i = tid; i < flen; i += ntot) {
      uint32_t v = (r == 0) ? i : frCur[i];
      uint32_t rv = rank[v];
      uint32_t s0 = sc[65536u + v] - N;
      uint32_t s1 = (v + 1 < N) ? (sc[65536u + v + 1] - N) : E;
      bool sel = true;
      for (uint32_t j = s0; j < s1; ++j) {
        if (cur[adj[j]] < rv) { sel = false; break; }  // dead >= DEADB > ranks
      }
      if (sel) mis[v] = 1;
    }
    gbar(bc, bk);
    // B: die if self-MIS, neighbor-MIS (any round), or neighbor dead BEFORE
    // this round (tag < r). Writes cur only; survivors build next frontier.
    uint32_t fpad = ((flen + ntot - 1) / ntot) * ntot;
    for (uint32_t i = tid; i < fpad; i += ntot) {
      bool valid = i < flen;
      uint32_t v = 0;
      bool die = false;
      if (valid) {
        v = (r == 0) ? i : frCur[i];
        die = (mis[v] != 0);
        if (!die) {
          uint32_t s0 = sc[65536u + v] - N;
          uint32_t s1 = (v + 1 < N) ? (sc[65536u + v + 1] - N) : E;
          for (uint32_t j = s0; j < s1; ++j) {
            uint32_t u = adj[j];
            if (mis[u] || (cur[u] - DEADB) < r) { die = true; break; }
          }
        }
        if (die) cur[v] = DEADB + r;
      }
      bool surv = valid && !die;
      uint64_t mb = __ballot(surv);
      if (mb) {
        uint32_t leader = (uint32_t)__ffsll((unsigned long long)mb) - 1u;
        uint32_t base = 0;
        if (lane == leader) base = atomicAdd(&cnt[1 + par], (uint32_t)__popcll(mb));
        base = (uint32_t)__shfl((int)base, (int)leader);
        if (surv) {
          uint32_t off = (uint32_t)__popcll(mb & ((1ull << lane) - 1ull));
          frNxt[base + off] = v;
        }
      }
    }
    gbar(bc, bk);
    flen = cnt[1 + par];
    uint32_t* t2 = frCur; frCur = frNxt; frNxt = t2;
    if (flen == 0) break;
  }

  // ---- P6: cluster assignment (gather, atomic-free) ----
  uint32_t M = grid_exscan(N, [=](uint32_t i) { return mis[i]; }, idpos, bsum, bc, bk);
  for (uint32_t v = tid; v < N; v += ntot) {
    if (mis[v]) {
      r2ip[rank[v]] = idpos[v];
      blist[idpos[v]] = v;  // MIS nodes in id order
      atomicMax(&cnt[4], rank[v]);
    }
  }
  gbar(bc, bk);
  {
    uint32_t maxrank = cnt[4];
    for (uint32_t v = tid; v < N; v += ntot) {
      uint32_t mv = mis[v] ? rank[v] : INF32;
      uint32_t s0 = sc[65536u + v] - N;
      uint32_t s1 = (v + 1 < N) ? (sc[65536u + v + 1] - N) : E;
      for (uint32_t j = s0; j < s1; ++j) {
        uint32_t u = adj[j];
        if (mis[u]) { uint32_t ru = rank[u]; if (ru < mv) mv = ru; }
      }
      clus[v] = r2ip[(mv == INF32) ? maxrank : mv];  // orphan: clamped OOB gather
    }
  }
  gbar(bc, bk);

  // ---- P7: coarse edges (unique off-diagonal pairs, lexicographic) ----
  uint64_t M2 = (uint64_t)M * (uint64_t)M;
  uint32_t nwords = (uint32_t)((M2 + 31) >> 5);
  uint32_t* bitmap = dyn;
  uint32_t* wpre = bitmap + nwords;
  bool wsok = ((uint64_t)(dyn - w) + 2ull * nwords) <= (uint64_t)wcap;
  if (wsok) {
    for (uint32_t i = tid; i < nwords; i += ntot) bitmap[i] = 0;
    gbar(bc, bk);
    for (uint32_t e = tid; e < E; e += ntot) {
      uint32_t a = clus[(uint32_t)rowA[e]], b = clus[(uint32_t)colA[e]];
      if (a != b) {
        uint32_t key = a * M + b;
        atomicOr(&bitmap[key >> 5], 1u << (key & 31u));
      }
    }
    gbar(bc, bk);
    uint32_t nk = grid_exscan(
        nwords, [=](uint32_t i) { return (uint32_t)__popc(bitmap[i]); }, wpre,
        bsum, bc, bk);
    uint64_t oEI = (uint64_t)M * 128ull;
    uint64_t oEA = oEI + 2ull * nk;
    uint64_t oCL = oEA + nk;
    uint64_t oMIS = oCL + N;
    uint64_t oSC = oMIS + N;
    bool fits = (oSC + N) <= (uint64_t)out_size;
    if (fits) {
      for (uint32_t i = tid; i < nk; i += ntot) out[oEA + i] = 0.0f;
      for (uint32_t wd = tid; wd < nwords; wd += ntot) {
        uint32_t bits = bitmap[wd];
        uint32_t slot = wpre[wd];
        while (bits) {
          uint32_t bpos = (uint32_t)__ffs(bits) - 1u;
          bits &= bits - 1u;
          uint32_t key = (wd << 5) + bpos;
          uint32_t aa = key / M;
          uint32_t bb = key - aa * M;
          out[oEI + slot] = (float)aa;
          out[oEI + (uint64_t)nk + slot] = (float)bb;
          slot++;
        }
      }
      gbar(bc, bk);
      for (uint32_t e = tid; e < E; e += ntot) {
        uint32_t a = clus[(uint32_t)rowA[e]], b = clus[(uint32_t)colA[e]];
        if (a != b) {
          uint32_t key = a * M + b;
          uint32_t wd = key >> 5, bit = key & 31u;
          uint32_t slot = wpre[wd] + (uint32_t)__popc(bitmap[wd] & ((1u << bit) - 1u));
          atomicAdd(&out[oEA + slot], eattr[e]);
        }
      }
      // x gather (float4-vectorized), MIS rows in id order
      const float4* x4 = (const float4*)x;
      float4* o4 = (float4*)out;
      uint32_t xtot = M * 32u;
      for (uint32_t i = tid; i < xtot; i += ntot) {
        uint32_t row = i >> 5;
        o4[i] = x4[((uint64_t)blist[row] << 5) + (i & 31u)];
      }
      for (uint32_t v = tid; v < N; v += ntot) {
        out[oCL + v] = (float)clus[v];
        out[oMIS + v] = mis[v] ? 1.0f : 0.0f;
        out[oSC + v] = score[v];
      }
    }
  }
}

extern "C" void kernel_launch(void* const* d_in, const int* in_sizes, int n_in,
                              void* d_out, int out_size, void* d_ws, size_t ws_size,
                              hipStream_t stream) {
  (void)n_in;
  // Query full-residency grid once: blocks/CU * numCU, rounded down to a
  // multiple of NTHR (grid_exscan requires it), clamped to [NTHR, MAXBLK].
  // Cooperative launch then can never over-subscribe co-residency.
  static int grid = 0;
  if (grid == 0) {
    int dev = 0;
    (void)hipGetDevice(&dev);
    int cus = 256;
    hipDeviceProp_t prop;
    if (hipGetDeviceProperties(&prop, dev) == hipSuccess && prop.multiProcessorCount > 0)
      cus = prop.multiProcessorCount;
    int bpc = 0;
    long long g = 512;  // fallback: previous verified geometry
    if (hipOccupancyMaxActiveBlocksPerMultiprocessor(&bpc, (const void*)kmis_kernel,
                                                     NTHR, 0) == hipSuccess && bpc > 0)
      g = (long long)bpc * (long long)cus;
    if (g > MAXBLK) g = MAXBLK;
    g -= g % NTHR;
    if (g < NTHR) g = NTHR;
    grid = (int)g;
  }
  const float* x = (const float*)d_in[0];
  const int* eidx = (const int*)d_in[1];
  const float* eattr = (const float*)d_in[2];
  const float* score = (const float*)d_in[3];
  float* out = (float*)d_out;
  uint32_t* w = (uint32_t*)d_ws;
  int N = in_sizes[3];
  int E = in_sizes[2];
  long long osz = (long long)out_size;
  unsigned long long wcap = (unsigned long long)(ws_size / 4);
  void* args[] = {&x, &eidx, &eattr, &score, &out, &w, &N, &E, &osz, &wcap};
  hipLaunchCooperativeKernel((void*)kmis_kernel, dim3(grid), dim3(NTHR), args, 0,
                             stream);
}

// Round 2
// 1906.857 us; speedup vs baseline: 2.5012x; 2.5012x over previous
//
#include <hip/hip_runtime.h>
#include <stdint.h>

static constexpr int NBLK = 512;
static constexpr int NTHR = 256;
static constexpr int NTOT = NBLK * NTHR;
static constexpr uint32_t GSZ = (uint32_t)NBLK / 64u;  // blocks per arrive sub-counter
static constexpr uint32_t INF32 = 0x7fffffffu;
static constexpr uint32_t DEADB = 0x40000000u;  // death tag base: DEADB + round
static constexpr uint32_t MAGIC = 0x13579BDFu;

// Contention-free grid barrier.
// bc layout (u32 units, one 128B cacheline per hot word):
//   sub-arrive counter g at bc[g*32], g=0..63   (block b arrives at b&63)
//   master arrive at bc[2048]
//   release word  at bc[2080]
//   magic         at bc[2112]
// Region size: 2144 u32. Arrive RMWs spread over 64 lines; pollers read only
// the release line -> no same-line RMW/load contention (R1's 2x regression).
__device__ inline void gbar(uint32_t* bc, uint32_t& bk) {
  __syncthreads();
  if (threadIdx.x == 0) {
    __threadfence();   // release: drain + write back this XCD's L2
    bk++;
    uint32_t old = __hip_atomic_fetch_add(&bc[(blockIdx.x & 63u) << 5], 1u,
                                          __ATOMIC_RELAXED, __HIP_MEMORY_SCOPE_AGENT);
    if (old == bk * GSZ - 1u) {  // last of my 8-block group this round
      uint32_t m = __hip_atomic_fetch_add(&bc[2048], 1u, __ATOMIC_RELAXED,
                                          __HIP_MEMORY_SCOPE_AGENT);
      if (m == bk * 64u - 1u)    // last group overall -> release
        __hip_atomic_store(&bc[2080], bk, __ATOMIC_RELAXED, __HIP_MEMORY_SCOPE_AGENT);
    }
    uint32_t r = __hip_atomic_load(&bc[2080], __ATOMIC_RELAXED, __HIP_MEMORY_SCOPE_AGENT);
    while ((int32_t)(r - bk) < 0) {
      __builtin_amdgcn_s_sleep(4);  // ~256cy backoff: cut poll traffic 4x
      r = __hip_atomic_load(&bc[2080], __ATOMIC_RELAXED, __HIP_MEMORY_SCOPE_AGENT);
    }
    __threadfence();   // acquire: invalidate stale L1/L2 lines
  }
  __syncthreads();
}

// Hierarchical exclusive scan; out[i]=exclusive prefix, returns grand total.
template <typename F>
__device__ uint32_t grid_exscan(uint32_t L, F getv, uint32_t* __restrict__ out,
                                uint32_t* __restrict__ bsum, uint32_t* bc,
                                uint32_t& bk) {
  __shared__ uint32_t sh[NTHR];
  const uint32_t t = blockIdx.x * blockDim.x + threadIdx.x;
  const uint32_t chunk = (L + NTOT - 1) / NTOT;
  const uint32_t lo = t * chunk;
  const uint32_t hi = (lo + chunk < L) ? (lo + chunk) : L;
  uint32_t s = 0;
  for (uint32_t i = lo; i < hi; ++i) s += getv(i);
  sh[threadIdx.x] = s;
  __syncthreads();
  for (int off = 1; off < NTHR; off <<= 1) {
    uint32_t add = (threadIdx.x >= (uint32_t)off) ? sh[threadIdx.x - off] : 0u;
    __syncthreads();
    sh[threadIdx.x] += add;
    __syncthreads();
  }
  uint32_t excl_in_blk = sh[threadIdx.x] - s;
  if (threadIdx.x == NTHR - 1) bsum[blockIdx.x] = sh[NTHR - 1];
  gbar(bc, bk);
  if (blockIdx.x == 0) {
    constexpr int PER = NBLK / NTHR;  // 2
    uint32_t loc[PER];
    uint32_t ls = 0;
    for (int j = 0; j < PER; ++j) { loc[j] = bsum[threadIdx.x * PER + j]; ls += loc[j]; }
    __syncthreads();
    sh[threadIdx.x] = ls;
    __syncthreads();
    for (int off = 1; off < NTHR; off <<= 1) {
      uint32_t add = (threadIdx.x >= (uint32_t)off) ? sh[threadIdx.x - off] : 0u;
      __syncthreads();
      sh[threadIdx.x] += add;
      __syncthreads();
    }
    uint32_t run = sh[threadIdx.x] - ls;
    for (int j = 0; j < PER; ++j) { uint32_t v = loc[j]; bsum[threadIdx.x * PER + j] = run; run += v; }
    if (threadIdx.x == NTHR - 1) bsum[NBLK] = run;
  }
  gbar(bc, bk);
  uint32_t run = bsum[blockIdx.x] + excl_in_blk;
  for (uint32_t i = lo; i < hi; ++i) { uint32_t g = getv(i); out[i] = run; run += g; }
  gbar(bc, bk);
  return bsum[NBLK];
}

__global__ void __launch_bounds__(NTHR)
kmis_kernel(const float* __restrict__ x, const int* __restrict__ eidx,
            const float* __restrict__ eattr, const float* __restrict__ score,
            float* __restrict__ out, uint32_t* __restrict__ w,
            int N_, int E_, long long out_size, unsigned long long wcap) {
  const uint32_t N = (uint32_t)N_;
  const uint32_t E = (uint32_t)E_;
  const uint32_t tid = blockIdx.x * blockDim.x + threadIdx.x;
  const uint32_t lane = threadIdx.x & 63u;
  uint32_t bk = 0;

  // ---- workspace layout (u32 units) ----
  uint32_t* bc     = w;                    // 2144 (tree barrier region)
  uint32_t* cnt    = bc + 2144;            // 16
  uint32_t* bsum   = cnt + 16;             // NBLK+1
  uint32_t* hist64 = bsum + NBLK + 1;      // 65536
  uint32_t* sc     = hist64 + 65536;       // 65536 + N (combined scan output)
  uint32_t* cur64  = sc + 65536 + N;       // 65536 (bucket fill cursors)
  uint32_t* deg    = cur64 + 65536;        // N
  uint32_t* ccur   = deg + N;              // N (CSR fill cursors)
  uint32_t* keys   = ccur + N;             // N
  uint32_t* rank   = keys + N;             // N
  uint32_t* cur    = rank + N;             // N: rank if live, DEADB+round if dead
  uint32_t* mis    = cur + N;              // N
  uint32_t* blist  = mis + N;              // N (buckets; later MIS list id-order)
  uint32_t* frA    = blist + N;            // N
  uint32_t* frB    = frA + N;              // N
  uint32_t* idpos  = frB + N;              // N
  uint32_t* r2ip   = idpos + N;            // N
  uint32_t* clus   = r2ip + N;             // N
  uint32_t* adj    = clus + N;             // E (CSR neighbor array)
  uint32_t* dyn    = adj + E;              // bitmap + wpre

  const int* rowA = eidx;
  const int* colA = eidx + E;

  // ---- handshake: robust barrier-cell init (ws is poisoned 0xAA) ----
  if (blockIdx.x == 0 && threadIdx.x == 0) {
    for (uint32_t g = 0; g < 64u; ++g)
      __hip_atomic_store(&bc[g << 5], 0u, __ATOMIC_RELAXED, __HIP_MEMORY_SCOPE_AGENT);
    __hip_atomic_store(&bc[2048], 0u, __ATOMIC_RELAXED, __HIP_MEMORY_SCOPE_AGENT);
    __hip_atomic_store(&bc[2080], 0u, __ATOMIC_RELAXED, __HIP_MEMORY_SCOPE_AGENT);
    __threadfence();
    __hip_atomic_store(&bc[2112], MAGIC, __ATOMIC_RELAXED, __HIP_MEMORY_SCOPE_AGENT);
  }
  if (threadIdx.x == 0) {
    while (__hip_atomic_load(&bc[2112], __ATOMIC_RELAXED, __HIP_MEMORY_SCOPE_AGENT) != MAGIC)
      __builtin_amdgcn_s_sleep(1);
    __threadfence();
  }
  __syncthreads();

  // ---- P0: init ----
  for (uint32_t i = tid; i < 65536u; i += NTOT) { hist64[i] = 0; cur64[i] = 0; }
  for (uint32_t i = tid; i < N; i += NTOT) { deg[i] = 0; ccur[i] = 0; mis[i] = 0; }
  if (tid < 16) cnt[tid] = 0;
  gbar(bc, bk);

  // ---- P1: score keys + bucket histogram; CSR degree count ----
  for (uint32_t i = tid; i < N; i += NTOT) {
    uint32_t k = __float_as_uint(score[i]);  // monotone for x>=0
    keys[i] = k;
    atomicAdd(&hist64[k >> 16], 1u);
  }
  for (uint32_t e = tid; e < E; e += NTOT) atomicAdd(&deg[(uint32_t)rowA[e]], 1u);
  gbar(bc, bk);

  // ---- P2: combined exclusive scan (bucket starts | row_ptr+N) ----
  grid_exscan(65536u + N,
              [=](uint32_t i) { return (i < 65536u) ? hist64[i] : deg[i - 65536u]; },
              sc, bsum, bc, bk);
  // sc[b] = bucket start; sc[65536+v]-N = CSR row start; row end via v+1 (or E).

  // ---- P3: fill bucket lists + CSR adjacency ----
  for (uint32_t i = tid; i < N; i += NTOT) {
    uint32_t b = keys[i] >> 16;
    uint32_t p = sc[b] + atomicAdd(&cur64[b], 1u);
    blist[p] = i;
  }
  for (uint32_t e = tid; e < E; e += NTOT) {
    uint32_t r = (uint32_t)rowA[e];
    uint32_t p = (sc[65536u + r] - N) + atomicAdd(&ccur[r], 1u);
    adj[p] = (uint32_t)colA[e];
  }
  gbar(bc, bk);

  // ---- P4: exact stable ranks ----
  for (uint32_t i = tid; i < N; i += NTOT) {
    uint32_t ki = keys[i];
    uint32_t b = ki >> 16;
    uint32_t s0 = sc[b], s1 = sc[b + 1];   // sc[65536] == N, safe for b=65535
    uint32_t r = s0;
    for (uint32_t j = s0; j < s1; ++j) {
      uint32_t jj = blist[j];
      uint32_t kj = keys[jj];
      r += (kj < ki || (kj == ki && jj < i)) ? 1u : 0u;
    }
    rank[i] = r;
    cur[i] = r;
  }
  gbar(bc, bk);

  // ---- P5: node-centric MIS, 2 barriers/round, frontier-compacted ----
  uint32_t* frCur = frA;
  uint32_t* frNxt = frB;
  uint32_t flen = N;
  for (uint32_t r = 0; r < 4000u; ++r) {
    uint32_t par = r & 1u;
    if (tid == 0) cnt[1 + par] = 0;
    // A: select local minima among live (reads cur, writes mis only)
    for (uint32_t i = tid; i < flen; i += NTOT) {
      uint32_t v = (r == 0) ? i : frCur[i];
      uint32_t rv = rank[v];
      uint32_t s0 = sc[65536u + v] - N;
      uint32_t s1 = (v + 1 < N) ? (sc[65536u + v + 1] - N) : E;
      bool sel = true;
      for (uint32_t j = s0; j < s1; ++j) {
        if (cur[adj[j]] < rv) { sel = false; break; }  // dead >= DEADB > ranks
      }
      if (sel) mis[v] = 1;
    }
    gbar(bc, bk);
    // B: die if self-MIS, neighbor-MIS (any round), or neighbor dead BEFORE
    // this round (tag < r). Writes cur only; survivors build next frontier.
    uint32_t fpad = ((flen + NTOT - 1) / NTOT) * NTOT;
    for (uint32_t i = tid; i < fpad; i += NTOT) {
      bool valid = i < flen;
      uint32_t v = 0;
      bool die = false;
      if (valid) {
        v = (r == 0) ? i : frCur[i];
        die = (mis[v] != 0);
        if (!die) {
          uint32_t s0 = sc[65536u + v] - N;
          uint32_t s1 = (v + 1 < N) ? (sc[65536u + v + 1] - N) : E;
          for (uint32_t j = s0; j < s1; ++j) {
            uint32_t u = adj[j];
            if (mis[u] || (cur[u] - DEADB) < r) { die = true; break; }
          }
        }
        if (die) cur[v] = DEADB + r;
      }
      bool surv = valid && !die;
      uint64_t mb = __ballot(surv);
      if (mb) {
        uint32_t leader = (uint32_t)__ffsll((unsigned long long)mb) - 1u;
        uint32_t base = 0;
        if (lane == leader) base = atomicAdd(&cnt[1 + par], (uint32_t)__popcll(mb));
        base = (uint32_t)__shfl((int)base, (int)leader);
        if (surv) {
          uint32_t off = (uint32_t)__popcll(mb & ((1ull << lane) - 1ull));
          frNxt[base + off] = v;
        }
      }
    }
    gbar(bc, bk);
    flen = cnt[1 + par];
    uint32_t* t2 = frCur; frCur = frNxt; frNxt = t2;
    if (flen == 0) break;
  }

  // ---- P6: cluster assignment (gather, atomic-free) ----
  uint32_t M = grid_exscan(N, [=](uint32_t i) { return mis[i]; }, idpos, bsum, bc, bk);
  for (uint32_t v = tid; v < N; v += NTOT) {
    if (mis[v]) {
      r2ip[rank[v]] = idpos[v];
      blist[idpos[v]] = v;  // MIS nodes in id order
      atomicMax(&cnt[4], rank[v]);
    }
  }
  gbar(bc, bk);
  {
    uint32_t maxrank = cnt[4];
    for (uint32_t v = tid; v < N; v += NTOT) {
      uint32_t mv = mis[v] ? rank[v] : INF32;
      uint32_t s0 = sc[65536u + v] - N;
      uint32_t s1 = (v + 1 < N) ? (sc[65536u + v + 1] - N) : E;
      for (uint32_t j = s0; j < s1; ++j) {
        uint32_t u = adj[j];
        if (mis[u]) { uint32_t ru = rank[u]; if (ru < mv) mv = ru; }
      }
      clus[v] = r2ip[(mv == INF32) ? maxrank : mv];  // orphan: clamped OOB gather
    }
  }
  gbar(bc, bk);

  // ---- P7: coarse edges (unique off-diagonal pairs, lexicographic) ----
  uint64_t M2 = (uint64_t)M * (uint64_t)M;
  uint32_t nwords = (uint32_t)((M2 + 31) >> 5);
  uint32_t* bitmap = dyn;
  uint32_t* wpre = bitmap + nwords;
  bool wsok = ((uint64_t)(dyn - w) + 2ull * nwords) <= (uint64_t)wcap;
  if (wsok) {
    for (uint32_t i = tid; i < nwords; i += NTOT) bitmap[i] = 0;
    gbar(bc, bk);
    for (uint32_t e = tid; e < E; e += NTOT) {
      uint32_t a = clus[(uint32_t)rowA[e]], b = clus[(uint32_t)colA[e]];
      if (a != b) {
        uint32_t key = a * M + b;
        atomicOr(&bitmap[key >> 5], 1u << (key & 31u));
      }
    }
    gbar(bc, bk);
    uint32_t nk = grid_exscan(
        nwords, [=](uint32_t i) { return (uint32_t)__popc(bitmap[i]); }, wpre,
        bsum, bc, bk);
    uint64_t oEI = (uint64_t)M * 128ull;
    uint64_t oEA = oEI + 2ull * nk;
    uint64_t oCL = oEA + nk;
    uint64_t oMIS = oCL + N;
    uint64_t oSC = oMIS + N;
    bool fits = (oSC + N) <= (uint64_t)out_size;
    if (fits) {
      for (uint32_t i = tid; i < nk; i += NTOT) out[oEA + i] = 0.0f;
      for (uint32_t wd = tid; wd < nwords; wd += NTOT) {
        uint32_t bits = bitmap[wd];
        uint32_t slot = wpre[wd];
        while (bits) {
          uint32_t bpos = (uint32_t)__ffs(bits) - 1u;
          bits &= bits - 1u;
          uint32_t key = (wd << 5) + bpos;
          uint32_t aa = key / M;
          uint32_t bb = key - aa * M;
          out[oEI + slot] = (float)aa;
          out[oEI + (uint64_t)nk + slot] = (float)bb;
          slot++;
        }
      }
      gbar(bc, bk);
      for (uint32_t e = tid; e < E; e += NTOT) {
        uint32_t a = clus[(uint32_t)rowA[e]], b = clus[(uint32_t)colA[e]];
        if (a != b) {
          uint32_t key = a * M + b;
          uint32_t wd = key >> 5, bit = key & 31u;
          uint32_t slot = wpre[wd] + (uint32_t)__popc(bitmap[wd] & ((1u << bit) - 1u));
          atomicAdd(&out[oEA + slot], eattr[e]);
        }
      }
      // x gather (float4-vectorized), MIS rows in id order
      const float4* x4 = (const float4*)x;
      float4* o4 = (float4*)out;
      uint32_t xtot = M * 32u;
      for (uint32_t i = tid; i < xtot; i += NTOT) {
        uint32_t row = i >> 5;
        o4[i] = x4[((uint64_t)blist[row] << 5) + (i & 31u)];
      }
      for (uint32_t v = tid; v < N; v += NTOT) {
        out[oCL + v] = (float)clus[v];
        out[oMIS + v] = mis[v] ? 1.0f : 0.0f;
        out[oSC + v] = score[v];
      }
    }
  }
}

extern "C" void kernel_launch(void* const* d_in, const int* in_sizes, int n_in,
                              void* d_out, int out_size, void* d_ws, size_t ws_size,
                              hipStream_t stream) {
  (void)n_in;
  const float* x = (const float*)d_in[0];
  const int* eidx = (const int*)d_in[1];
  const float* eattr = (const float*)d_in[2];
  const float* score = (const float*)d_in[3];
  float* out = (float*)d_out;
  uint32_t* w = (uint32_t*)d_ws;
  int N = in_sizes[3];
  int E = in_sizes[2];
  long long osz = (long long)out_size;
  unsigned long long wcap = (unsigned long long)(ws_size / 4);
  void* args[] = {&x, &eidx, &eattr, &score, &out, &w, &N, &E, &osz, &wcap};
  hipLaunchCooperativeKernel((void*)kmis_kernel, dim3(NBLK), dim3(NTHR), args, 0,
                             stream);
}